// Round 3
// baseline (264.413 us; speedup 1.0000x reference)
//
#include <hip/hip_runtime.h>
#include <math.h>

// ---------------------------------------------------------------------------
// JAX Threefry-2x32 (constexpr for key derivation, device for per-elem hash).
// ---------------------------------------------------------------------------
struct K2 { unsigned a, b; };

__host__ __device__ constexpr unsigned rotl32c(unsigned x, int r) {
  return (x << r) | (x >> (32 - r));
}

__host__ __device__ constexpr K2 threefry2x32(unsigned k0, unsigned k1,
                                              unsigned x0, unsigned x1) {
  const unsigned ks2 = k0 ^ k1 ^ 0x1BD11BDAu;
  const unsigned ks[3] = {k0, k1, ks2};
  const int rotA[4] = {13, 15, 26, 6};
  const int rotB[4] = {17, 29, 16, 24};
  x0 += k0; x1 += k1;
  for (int g = 0; g < 5; ++g) {
    const int* rr = (g & 1) ? rotB : rotA;
    for (int i = 0; i < 4; ++i) {
      x0 += x1;
      x1 = rotl32c(x1, rr[i]);
      x1 ^= x0;
    }
    x0 += ks[(g + 1) % 3];
    x1 += ks[(g + 2) % 3] + (unsigned)(g + 1);
  }
  return K2{x0, x1};
}

__host__ __device__ constexpr K2 hop_key(unsigned k) {
  K2 f = threefry2x32(0u, 42u, 0u, k);
  return threefry2x32(f.a, f.b, 0u, 1u);
}

constexpr K2 HK0 = hop_key(0u);
constexpr K2 HK1 = hop_key(1u);

// ---------------------------------------------------------------------------
// Hop-1 sampling: s1[i] = adj[node_ids[i/10]*128 + ((w0^w1)&127)]
// ---------------------------------------------------------------------------
__global__ __launch_bounds__(256) void sample_hop1(
    const int* __restrict__ ids, const int* __restrict__ adj,
    int* __restrict__ out, int n) {
  int i = blockIdx.x * 256 + threadIdx.x;
  if (i >= n) return;
  K2 r = threefry2x32(HK0.a, HK0.b, 0u, (unsigned)i);
  int col = (int)((r.a ^ r.b) & 127u);
  out[i] = adj[(long long)ids[i / 10] * 128 + col];
}

// ---------------------------------------------------------------------------
// Fused hop-2 sample + gather-mean. One wave per output row (10240 rows).
// ---------------------------------------------------------------------------
__global__ __launch_bounds__(256) void sample_mean_hop2(
    const int* __restrict__ s1, const int* __restrict__ adj,
    const float* __restrict__ feat, float* __restrict__ dst) {
  const int m = blockIdx.x * 4 + (threadIdx.x >> 6);
  const int lane = threadIdx.x & 63;

  const int nid = s1[m];  // wave-uniform
  int srow;
  {
    unsigned i = (unsigned)(m * 25 + (lane < 25 ? lane : 0));
    K2 r = threefry2x32(HK1.a, HK1.b, 0u, i);
    int col = (int)((r.a ^ r.b) & 127u);
    srow = adj[(long long)nid * 128 + col];
  }

  float4 acc = make_float4(0.f, 0.f, 0.f, 0.f);
#pragma unroll
  for (int c = 0; c < 25; c += 5) {
    float4 v[5];
#pragma unroll
    for (int j = 0; j < 5; ++j) {
      long long row = (long long)__shfl(srow, c + j, 64);
      v[j] = *(const float4*)(feat + row * 256 + (lane << 2));
    }
#pragma unroll
    for (int j = 0; j < 5; ++j) {
      acc.x += v[j].x; acc.y += v[j].y; acc.z += v[j].z; acc.w += v[j].w;
    }
  }
  const float invS = 1.f / 25.f;
  acc.x *= invS; acc.y *= invS; acc.z *= invS; acc.w *= invS;
  *(float4*)(dst + (long long)m * 256 + (lane << 2)) = acc;
}

// ---------------------------------------------------------------------------
// Wave-per-row mean of S rows (gathered via idx, or contiguous groups).
// ---------------------------------------------------------------------------
template <int S>
__global__ __launch_bounds__(256) void mean_rows_w(
    const float* __restrict__ src, const int* __restrict__ idx,
    float* __restrict__ dst, float invS) {
  const int m = blockIdx.x * 4 + (threadIdx.x >> 6);
  const int lane = threadIdx.x & 63;
  const long long base = (long long)m * S;

  int srow = 0;
  if (idx) srow = idx[base + (lane < S ? lane : 0)];

  float4 acc = make_float4(0.f, 0.f, 0.f, 0.f);
#pragma unroll
  for (int c = 0; c < S; c += 5) {
    float4 v[5];
#pragma unroll
    for (int j = 0; j < 5; ++j) {
      if (c + j < S) {
        long long row = idx ? (long long)__shfl(srow, c + j, 64) : (base + c + j);
        v[j] = *(const float4*)(src + row * 256 + (lane << 2));
      }
    }
#pragma unroll
    for (int j = 0; j < 5; ++j) {
      if (c + j < S) {
        acc.x += v[j].x; acc.y += v[j].y; acc.z += v[j].z; acc.w += v[j].w;
      }
    }
  }
  acc.x *= invS; acc.y *= invS; acc.z *= invS; acc.w *= invS;
  *(float4*)(dst + (long long)m * 256 + (lane << 2)) = acc;
}

// ---------------------------------------------------------------------------
// Multi-config gather-A GEMM + ReLU, flat 1D tile decode.
// C[m, ccol0 + nt*BN + n] = relu(A[row(m)] @ B[:, nt*BN+n])
// A: [*,256] fp32 (row via idx or identity), B: [256,128] row-major.
// Template: BM x BN tile, TM x TN micro-tile, 256 threads, BK=16,
// 1-deep global prefetch pipeline.
// ---------------------------------------------------------------------------
struct GemmCfg {
  const float* A; const int* idx; const float* B; float* C;
  int ccol0; int mtiles; int ntiles;  // ntiles = total tiles (m*n)
};
struct GemmCfg4 { GemmCfg c[4]; };

template <int BM, int BN, int TM, int TN>
__global__ __launch_bounds__(256) void gemm_relu_multi(GemmCfg4 cfgs) {
  int b = blockIdx.x;
  int z = 0;
  while (z < 3 && b >= cfgs.c[z].ntiles) { b -= cfgs.c[z].ntiles; ++z; }
  const GemmCfg cfg = cfgs.c[z];
  const int mt = b % cfg.mtiles;
  const int nt = b / cfg.mtiles;

  __shared__ __align__(16) float As[16][BM + 4];  // transposed A tile
  __shared__ __align__(16) float Bs[16][BN + 4];

  const int t = threadIdx.x;
  const int tx = t & 15, ty = t >> 4;

  constexpr int A4 = BM / 64;  // float4 loads per thread for A (2 or 1)
  constexpr int B4 = BN / 64;

  // A load mapping: BM rows x 16 k, contiguous floats per thread
  int arow, akb;
  if constexpr (BM == 128) { arow = t >> 1; akb = (t & 1) << 3; }
  else { arow = t >> 2; akb = (t & 3) << 2; }
  const int grow = mt * BM + arow;
  const long long asrc = cfg.idx ? (long long)cfg.idx[grow] : (long long)grow;
  const float* Ap = cfg.A + asrc * 256 + akb;

  // B load mapping: 16 k-rows x BN cols
  const int bkk = t >> 4;
  const int bnb = (t & 15) * (BN / 16);
  const float* Bp = cfg.B + bkk * 128 + nt * BN + bnb;

  float4 av[A4], bv[B4];
#pragma unroll
  for (int u = 0; u < A4; ++u) av[u] = *(const float4*)(Ap + (u << 2));
#pragma unroll
  for (int u = 0; u < B4; ++u) bv[u] = *(const float4*)(Bp + (u << 2));

  float acc[TM][TN] = {};

  for (int k0 = 0; k0 < 256; k0 += 16) {
    __syncthreads();
#pragma unroll
    for (int u = 0; u < A4; ++u) {
      As[akb + (u << 2) + 0][arow] = av[u].x;
      As[akb + (u << 2) + 1][arow] = av[u].y;
      As[akb + (u << 2) + 2][arow] = av[u].z;
      As[akb + (u << 2) + 3][arow] = av[u].w;
    }
#pragma unroll
    for (int u = 0; u < B4; ++u)
      *(float4*)&Bs[bkk][bnb + (u << 2)] = bv[u];
    __syncthreads();

    if (k0 + 16 < 256) {  // prefetch next K-slab (hides global latency)
#pragma unroll
      for (int u = 0; u < A4; ++u)
        av[u] = *(const float4*)(Ap + k0 + 16 + (u << 2));
#pragma unroll
      for (int u = 0; u < B4; ++u)
        bv[u] = *(const float4*)(Bp + (long long)(k0 + 16) * 128 + (u << 2));
    }

#pragma unroll
    for (int kk = 0; kk < 16; ++kk) {
      float a[TM], bb[TN];
#pragma unroll
      for (int u = 0; u < TM; u += 4)
        *(float4*)&a[u] = *(const float4*)&As[kk][ty * TM + u];
#pragma unroll
      for (int u = 0; u < TN; u += 4)
        *(float4*)&bb[u] = *(const float4*)&Bs[kk][tx * TN + u];
#pragma unroll
      for (int i = 0; i < TM; ++i)
#pragma unroll
        for (int j = 0; j < TN; ++j)
          acc[i][j] += a[i] * bb[j];
    }
  }

#pragma unroll
  for (int i = 0; i < TM; ++i) {
    const int r = mt * BM + ty * TM + i;
    float* Cp = cfg.C + (long long)r * 256 + cfg.ccol0 + nt * BN + tx * TN;
#pragma unroll
    for (int j = 0; j < TN; ++j) {
      float v = acc[i][j];
      Cp[j] = v > 0.f ? v : 0.f;
    }
  }
}

// ---------------------------------------------------------------------------
// Final: out[m] = (h[m] . w_out) / sqrt(max(|h[m]|^2, 1e-12)) + b_out
// ---------------------------------------------------------------------------
__global__ __launch_bounds__(256) void final_kernel(
    const float* __restrict__ h, const float* __restrict__ w,
    const float* __restrict__ b, float* __restrict__ out) {
  const int m = blockIdx.x;
  const int t = threadIdx.x;
  float v = h[(long long)m * 256 + t];
  float wv = w[t];
  float ss = v * v;
  float dd = v * wv;
  for (int off = 32; off; off >>= 1) {
    ss += __shfl_down(ss, off, 64);
    dd += __shfl_down(dd, off, 64);
  }
  __shared__ float s1[4], s2[4];
  const int wid = t >> 6, lane = t & 63;
  if (lane == 0) { s1[wid] = ss; s2[wid] = dd; }
  __syncthreads();
  if (t == 0) {
    float S = s1[0] + s1[1] + s1[2] + s1[3];
    float D = s2[0] + s2[1] + s2[2] + s2[3];
    float n = sqrtf(fmaxf(S, 1e-12f));
    out[m] = D / n + b[0];
  }
}

// ---------------------------------------------------------------------------
extern "C" void kernel_launch(void* const* d_in, const int* in_sizes, int n_in,
                              void* d_out, int out_size, void* d_ws, size_t ws_size,
                              hipStream_t stream) {
  (void)in_sizes; (void)n_in; (void)out_size; (void)ws_size;

  const float* features  = (const float*)d_in[0];  // [100000,256]
  const float* w_self_0  = (const float*)d_in[1];  // [256,128]
  const float* w_neigh_0 = (const float*)d_in[2];  // [256,128]
  const float* w_self_1  = (const float*)d_in[3];  // [256,128]
  const float* w_neigh_1 = (const float*)d_in[4];  // [256,128]
  const float* w_out     = (const float*)d_in[5];  // [256,1]
  const float* b_out     = (const float*)d_in[6];  // [1]
  const int*   node_ids  = (const int*)d_in[7];    // [1024]
  const int*   adj       = (const int*)d_in[8];    // [100000,128]
  float* out = (float*)d_out;                      // [1024]

  char* ws = (char*)d_ws;
  size_t off = 0;
  auto alloc = [&](size_t bytes) -> void* {
    void* p = ws + off;
    off = (off + bytes + 255) & ~(size_t)255;
    return p;
  };
  int*   s1   = (int*)alloc(10240 * sizeof(int));
  float* nm1  = (float*)alloc((size_t)10240 * 256 * 4);
  float* nm0  = (float*)alloc((size_t)1024 * 256 * 4);
  float* out1 = (float*)alloc((size_t)10240 * 256 * 4);
  float* out0 = (float*)alloc((size_t)1024 * 256 * 4);
  float* nml1 = (float*)alloc((size_t)1024 * 256 * 4);
  float* hbuf = (float*)alloc((size_t)1024 * 256 * 4);

  // 1) hop-1 sampling (bit-exact JAX threefry)
  sample_hop1<<<40, 256, 0, stream>>>(node_ids, adj, s1, 10240);

  // 2) fused hop-2 sample + gather-mean; hop-1 gather-mean
  sample_mean_hop2<<<2560, 256, 0, stream>>>(s1, adj, features, nm1);
  mean_rows_w<10><<<256, 256, 0, stream>>>(features, s1, nm0, 0.1f);

  // 3) layer 0: four GEMMs, one dispatch, 128x128 tiles, flat decode
  {
    GemmCfg4 cf;
    cf.c[0] = {features, s1,       w_self_0,  out1, 0,   80, 80};
    cf.c[1] = {nm1,      nullptr,  w_neigh_0, out1, 128, 80, 80};
    cf.c[2] = {features, node_ids, w_self_0,  out0, 0,   8,  8};
    cf.c[3] = {nm0,      nullptr,  w_neigh_0, out0, 128, 8,  8};
    gemm_relu_multi<128, 128, 8, 8><<<176, 256, 0, stream>>>(cf);
  }

  // 4) layer 1
  mean_rows_w<10><<<256, 256, 0, stream>>>(out1, nullptr, nml1, 0.1f);
  {
    GemmCfg4 cf;
    cf.c[0] = {out0, nullptr, w_self_1,  hbuf, 0,   16, 32};
    cf.c[1] = {nml1, nullptr, w_neigh_1, hbuf, 128, 16, 32};
    cf.c[2] = {nullptr, nullptr, nullptr, nullptr, 0, 1, 0};
    cf.c[3] = {nullptr, nullptr, nullptr, nullptr, 0, 1, 0};
    gemm_relu_multi<64, 64, 4, 4><<<64, 256, 0, stream>>>(cf);
  }

  // 5) l2-normalize + Dense(1)
  final_kernel<<<1024, 256, 0, stream>>>(hbuf, w_out, b_out, out);
}